// Round 4
// baseline (2740.303 us; speedup 1.0000x reference)
//
#include <hip/hip_runtime.h>
#include <hip/hip_bf16.h>
#include <math.h>

#define B_ 2048
#define L_ 32
#define V_ 1024
#define E_ 256
#define H_ 512
#define DEC_T_ 7
#define NA_ (B_ * H_)

typedef unsigned short u16;
typedef unsigned int u32;
using bf16x8 = __attribute__((ext_vector_type(8))) short;
using f32x4  = __attribute__((ext_vector_type(4))) float;

__device__ __forceinline__ u16 f2b(float f) {
  union { float f; u32 i; } x; x.f = f;
  u32 r = x.i + 0x7FFFu + ((x.i >> 16) & 1u);
  return (u16)(r >> 16);
}
__device__ __forceinline__ float b2f(u16 u) {
  union { u32 i; float f; } x; x.i = ((u32)u) << 16; return x.f;
}
__device__ __forceinline__ float sigm(float x) { return 1.f / (1.f + __expf(-x)); }
__device__ __forceinline__ float tanhfast(float x) {
  const float xx = fminf(fmaxf(x, -15.f), 15.f);
  const float e = __expf(2.f * xx);
  return (e - 1.f) / (e + 1.f);
}

// async global->LDS, 16B per lane. dest = wave-uniform base + lane*16.
__device__ __forceinline__ void gl_lds16(const void* g, void* l) {
  __builtin_amdgcn_global_load_lds((const __attribute__((address_space(1))) u32*)g,
                                   (__attribute__((address_space(3))) u32*)l, 16, 0, 0);
}

// ---------------------------------------------------------------------------
// Grid barrier (generation counter), REGULAR launch. Co-residency is
// guaranteed by capacity: 32KB LDS -> 5 blocks/CU, 84 VGPR -> >=5 blocks/CU,
// so capacity >= 1280 blocks >> grid (512). All blocks are placed before any
// can stall at the barrier; stream is serial so no other kernel holds CUs.
// Bounded spin: on (impossible) timeout we fall through -> wrong answer with
// counters, never a hang. Replay-safe: gen is read fresh, cnt self-resets.
// ---------------------------------------------------------------------------
__device__ __forceinline__ void gbar(unsigned* cnt, unsigned* gen, unsigned nblk) {
  __syncthreads();
  if (threadIdx.x == 0) {
    __threadfence();  // release: my h-writes visible device-wide
    const unsigned g = __hip_atomic_load(gen, __ATOMIC_RELAXED, __HIP_MEMORY_SCOPE_AGENT);
    const unsigned v = __hip_atomic_fetch_add(cnt, 1u, __ATOMIC_RELAXED, __HIP_MEMORY_SCOPE_AGENT);
    if (v == nblk - 1u) {
      __hip_atomic_store(cnt, 0u, __ATOMIC_RELAXED, __HIP_MEMORY_SCOPE_AGENT);
      __hip_atomic_store(gen, g + 1u, __ATOMIC_RELEASE, __HIP_MEMORY_SCOPE_AGENT);
    } else {
      for (int it = 0; it < (1 << 22); ++it) {
        if (__hip_atomic_load(gen, __ATOMIC_RELAXED, __HIP_MEMORY_SCOPE_AGENT) != g) break;
        __builtin_amdgcn_s_sleep(2);
      }
    }
    __threadfence();  // acquire: see others' h-writes
  }
  __syncthreads();
}

// ---------------------------------------------------------------------------
// LDS tiles [128 rows][32 bf16] linear, double-buffered; 16B chunks
// XOR-swizzled on the GLOBAL source (linear LDS dest, gl_lds16) and on the
// ds_read address with the same involution -> conflict-free (verified R2:
// SQ_LDS_BANK_CONFLICT = 0).
// ---------------------------------------------------------------------------

// Persistent bidirectional encoder: 32 LSTM steps in ONE launch.
// 512 blocks = (dir, jblk, mblk); XCD-contiguous mapping. c in registers.
__launch_bounds__(256, 2)
__global__ void enc_persist_k(const int* __restrict__ feat, const u16* __restrict__ emb,
                              const u16* __restrict__ Wf, const u16* __restrict__ Wbk,
                              const float* __restrict__ bsf, const float* __restrict__ bsb,
                              u16* hfa, u16* hfb, u16* hba, u16* hbb,
                              unsigned* bar) {
  __shared__ u16 Wt[2][128 * 32];
  __shared__ u16 At[2][128 * 32];
  const int tid = threadIdx.x;
  const int lane = tid & 63, wave = tid >> 6;
  const int wr = wave & 1, wc = wave >> 1;
  const int bid = blockIdx.x;
  const int l = (bid & 7) * 64 + (bid >> 3);          // XCD-contiguous logical id
  const int dir = l >> 8;
  const int j0 = (l & 15) * 128;
  const int m0 = (((l >> 6) & 3) * 4 + ((l >> 4) & 3)) * 128;
  const u16* W = dir ? Wbk : Wf;
  const float* bsum = dir ? bsb : bsf;
  u16* hA = dir ? hba : hfa;
  u16* hB = dir ? hbb : hfb;
  unsigned* cnt = bar + dir * 2;
  unsigned* gen = bar + dir * 2 + 1;

  const int lr = lane & 15;
  const int swk = ((lane >> 4) ^ ((lane >> 1) & 3)) * 8;   // swizzled read chunk
  const int srow = wave * 32 + (lane >> 2);
  const int csrc = ((lane & 3) ^ ((lane >> 3) & 3)) * 8;   // swizzled src chunk
  const u16* wsrc0 = W + (j0 + srow) * (E_ + H_) + csrc;
  const u16* wsrc1 = wsrc0 + 16 * (E_ + H_);
  u16* wdst0 = &Wt[0][(wave * 32) * 32];
  u16* wdst1 = wdst0 + 16 * 32;
  u16* adst0 = &At[0][(wave * 32) * 32];
  u16* adst1 = adst0 + 16 * 32;
  u16* hlds = &Wt[0][0];                                   // reused post-K-loop
  const int frow0 = (m0 + srow) * L_;
  const int frow1 = (m0 + srow + 16) * L_;
  const int jb_base = j0 + wr * 64 + (lane >> 4) * 4;
  const int n0 = j0 >> 2;                                  // block's 32-wide n range

  float creg[4][4] = {};                                   // cell state, in regs

  for (int s = 0; s < L_; ++s) {
    const int tc = dir ? (L_ - 1 - s) : s;
    const int t0 = feat[frow0 + tc], t1 = feat[frow1 + tc];
    const u16* e0 = emb + t0 * E_ + csrc;
    const u16* e1 = emb + t1 * E_ + csrc;
    const u16* hin = (s & 1) ? hB : hA;
    u16* hout = (s & 1) ? hA : hB;
    const u16* h0 = hin + (m0 + srow) * H_ + csrc - E_;    // h0 + k0 valid for k0 >= E_
    const u16* h1 = h0 + 16 * H_;

    if (s) gbar(cnt, gen, 256);                            // h(s-1) visible

    // stage kt=0 -> buf0, kt=1 -> buf1 (both k-tiles are in the emb range)
    gl_lds16(wsrc0, wdst0);            gl_lds16(wsrc1, wdst1);
    gl_lds16(e0, adst0);               gl_lds16(e1, adst1);
    gl_lds16(wsrc0 + 32, wdst0 + 4096); gl_lds16(wsrc1 + 32, wdst1 + 4096);
    gl_lds16(e0 + 32, adst0 + 4096);    gl_lds16(e1 + 32, adst1 + 4096);
    __syncthreads();

    f32x4 acc[4][4] = {};
    int cur = 0;
    for (int kt = 0; kt < 24; ++kt) {
      if (kt >= 1 && kt + 1 < 24) {                        // kt=1 pre-staged
        const int k0 = (kt + 1) << 5;
        const int bo = (cur ^ 1) * 4096;
        gl_lds16(wsrc0 + k0, wdst0 + bo);
        gl_lds16(wsrc1 + k0, wdst1 + bo);
        if (k0 < E_) { gl_lds16(e0 + k0, adst0 + bo); gl_lds16(e1 + k0, adst1 + bo); }
        else         { gl_lds16(h0 + k0, adst0 + bo); gl_lds16(h1 + k0, adst1 + bo); }
      }
      const u16* Wb2 = &Wt[cur][0];
      const u16* Ab2 = &At[cur][0];
      bf16x8 af[4], bb[4];
#pragma unroll
      for (int t = 0; t < 4; ++t) {
        af[t] = *(const bf16x8*)(Wb2 + (wr * 64 + t * 16 + lr) * 32 + swk);
        bb[t] = *(const bf16x8*)(Ab2 + (wc * 64 + t * 16 + lr) * 32 + swk);
      }
#pragma unroll
      for (int i = 0; i < 4; ++i)
#pragma unroll
        for (int j = 0; j < 4; ++j)
          acc[i][j] = __builtin_amdgcn_mfma_f32_16x16x32_bf16(af[i], bb[j], acc[i][j], 0, 0, 0);
      __syncthreads();                                     // drains staged vmcnt
      cur ^= 1;
    }

    // epilogue: gates -> cell update in regs, h tile via LDS
#pragma unroll
    for (int i = 0; i < 4; ++i) {
      const int jb = jb_base + i * 16;
      const float4 bs = *(const float4*)(bsum + jb);
      const int nloc = (jb - j0) >> 2;                     // 0..31
#pragma unroll
      for (int j = 0; j < 4; ++j) {
        const int mloc = wc * 64 + j * 16 + lr;
        const float gi = acc[i][j][0] + bs.x;
        const float gf = acc[i][j][1] + bs.y;
        const float gg = acc[i][j][2] + bs.z;
        const float go = acc[i][j][3] + bs.w;
        const float cn = sigm(gf) * creg[i][j] + sigm(gi) * tanhfast(gg);
        creg[i][j] = cn;
        hlds[mloc * 32 + nloc] = f2b(sigm(go) * tanhfast(cn));
      }
    }
    __syncthreads();
    // coalesced h write: 512 16B chunks, 2 per thread
#pragma unroll
    for (int cc = 0; cc < 2; ++cc) {
      const int ch = tid + cc * 256;
      const int row = ch >> 2, cpos = (ch & 3) * 8;
      *(uint4*)(hout + (m0 + row) * H_ + n0 + cpos) = *(const uint4*)(hlds + row * 32 + cpos);
    }
  }
}

// Persistent decoder: 7 LSTM steps in ONE launch. 256 blocks (jblk, mblk);
// c0 = z read once from dc (fp32 [n][m]); h history written to dech[t].
__launch_bounds__(256, 2)
__global__ void dec_persist_k(const u16* __restrict__ Wd, const float* __restrict__ bsd,
                              const u16* __restrict__ dz, const float* __restrict__ dcc,
                              u16* dech, unsigned* bar) {
  __shared__ u16 Wt[2][128 * 32];
  __shared__ u16 At[2][128 * 32];
  const int tid = threadIdx.x;
  const int lane = tid & 63, wave = tid >> 6;
  const int wr = wave & 1, wc = wave >> 1;
  const int bid = blockIdx.x;
  const int l = (bid & 7) * 32 + (bid >> 3);
  const int j0 = (l & 15) * 128;
  const int m0 = ((l >> 5) * 2 + ((l >> 4) & 1)) * 128;
  unsigned* cnt = bar + 4;
  unsigned* gen = bar + 5;

  const int lr = lane & 15;
  const int swk = ((lane >> 4) ^ ((lane >> 1) & 3)) * 8;
  const int srow = wave * 32 + (lane >> 2);
  const int csrc = ((lane & 3) ^ ((lane >> 3) & 3)) * 8;
  const u16* wsrc0 = Wd + (j0 + srow) * H_ + csrc;
  const u16* wsrc1 = wsrc0 + 16 * H_;
  u16* wdst0 = &Wt[0][(wave * 32) * 32];
  u16* wdst1 = wdst0 + 16 * 32;
  u16* adst0 = &At[0][(wave * 32) * 32];
  u16* adst1 = adst0 + 16 * 32;
  u16* hlds = &Wt[0][0];
  const int jb_base = j0 + wr * 64 + (lane >> 4) * 4;
  const int n0 = j0 >> 2;

  float creg[4][4];
#pragma unroll
  for (int i = 0; i < 4; ++i) {
    const int n = (jb_base + i * 16) >> 2;
#pragma unroll
    for (int j = 0; j < 4; ++j)
      creg[i][j] = dcc[n * B_ + (m0 + wc * 64 + j * 16 + lr)];
  }

  for (int t = 0; t < DEC_T_; ++t) {
    const u16* hin = t ? (dech + (long)(t - 1) * NA_) : dz;
    u16* hout = dech + (long)t * NA_;
    const u16* h0 = hin + (m0 + srow) * H_ + csrc;
    const u16* h1 = h0 + 16 * H_;

    if (t) gbar(cnt, gen, 256);

    gl_lds16(wsrc0, wdst0);            gl_lds16(wsrc1, wdst1);
    gl_lds16(h0, adst0);               gl_lds16(h1, adst1);
    gl_lds16(wsrc0 + 32, wdst0 + 4096); gl_lds16(wsrc1 + 32, wdst1 + 4096);
    gl_lds16(h0 + 32, adst0 + 4096);    gl_lds16(h1 + 32, adst1 + 4096);
    __syncthreads();

    f32x4 acc[4][4] = {};
    int cur = 0;
    for (int kt = 0; kt < 16; ++kt) {
      if (kt >= 1 && kt + 1 < 16) {
        const int k0 = (kt + 1) << 5;
        const int bo = (cur ^ 1) * 4096;
        gl_lds16(wsrc0 + k0, wdst0 + bo);
        gl_lds16(wsrc1 + k0, wdst1 + bo);
        gl_lds16(h0 + k0, adst0 + bo);
        gl_lds16(h1 + k0, adst1 + bo);
      }
      const u16* Wb2 = &Wt[cur][0];
      const u16* Ab2 = &At[cur][0];
      bf16x8 af[4], bb[4];
#pragma unroll
      for (int tt = 0; tt < 4; ++tt) {
        af[tt] = *(const bf16x8*)(Wb2 + (wr * 64 + tt * 16 + lr) * 32 + swk);
        bb[tt] = *(const bf16x8*)(Ab2 + (wc * 64 + tt * 16 + lr) * 32 + swk);
      }
#pragma unroll
      for (int i = 0; i < 4; ++i)
#pragma unroll
        for (int j = 0; j < 4; ++j)
          acc[i][j] = __builtin_amdgcn_mfma_f32_16x16x32_bf16(af[i], bb[j], acc[i][j], 0, 0, 0);
      __syncthreads();
      cur ^= 1;
    }

#pragma unroll
    for (int i = 0; i < 4; ++i) {
      const int jb = jb_base + i * 16;
      const float4 bs = *(const float4*)(bsd + jb);
      const int nloc = (jb - j0) >> 2;
#pragma unroll
      for (int j = 0; j < 4; ++j) {
        const int mloc = wc * 64 + j * 16 + lr;
        const float gi = acc[i][j][0] + bs.x;
        const float gf = acc[i][j][1] + bs.y;
        const float gg = acc[i][j][2] + bs.z;
        const float go = acc[i][j][3] + bs.w;
        const float cn = sigm(gf) * creg[i][j] + sigm(gi) * tanhfast(gg);
        creg[i][j] = cn;
        hlds[mloc * 32 + nloc] = f2b(sigm(go) * tanhfast(cn));
      }
    }
    __syncthreads();
#pragma unroll
    for (int cc = 0; cc < 2; ++cc) {
      const int ch = tid + cc * 256;
      const int row = ch >> 2, cpos = (ch & 3) * 8;
      *(uint4*)(hout + (m0 + row) * H_ + n0 + cpos) = *(const uint4*)(hlds + row * 32 + cpos);
    }
  }
}

// ---------------------------------------------------------------------------
// Plain bf16 GEMM + bias: C[m][v] = A[m]*W[v] + bias[v], fp32 out.
// ldc==0 => ff mode: row m encodes (t=m>>11, b=m&2047), C index b*7V+t*V+v.
// ---------------------------------------------------------------------------
struct OP {
  const u16* A;       // M x K bf16
  const u16* W;       // N x K bf16
  const float* bias;  // N fp32
  float* Cf;
  int ldc;            // 0 => ff (t,b) mode
  int K;
};

__launch_bounds__(256)
__global__ void out_mfma_k(OP p0, OP p1) {
  OP p = blockIdx.z ? p1 : p0;
  __shared__ u16 Ws[2][128 * 32];
  __shared__ u16 As[2][128 * 32];
  const int tid = threadIdx.x;
  const int lane = tid & 63, wave = tid >> 6;
  const int wr = wave & 1, wc = wave >> 1;
  const int v0 = blockIdx.x * 128, m0 = blockIdx.y * 128;
  const int lr = lane & 15;
  const int swk = ((lane >> 4) ^ ((lane >> 1) & 3)) * 8;

  const int srow = wave * 32 + (lane >> 2);
  const int csrc = ((lane & 3) ^ ((lane >> 3) & 3)) * 8;
  const u16* wsrc0 = p.W + (v0 + srow) * p.K + csrc;
  const u16* wsrc1 = wsrc0 + 16 * p.K;
  const u16* asrc0 = p.A + (m0 + srow) * p.K + csrc;
  const u16* asrc1 = asrc0 + 16 * p.K;
  u16* wdst0 = &Ws[0][(wave * 32) * 32];
  u16* wdst1 = wdst0 + 16 * 32;
  u16* adst0 = &As[0][(wave * 32) * 32];
  u16* adst1 = adst0 + 16 * 32;

  f32x4 acc[4][4] = {};
  const int NT = p.K >> 5;

  auto stage = [&](int kt, int buf) {
    const int k0 = kt << 5;
    const int bo = buf * 4096;
    gl_lds16(wsrc0 + k0, wdst0 + bo);
    gl_lds16(wsrc1 + k0, wdst1 + bo);
    gl_lds16(asrc0 + k0, adst0 + bo);
    gl_lds16(asrc1 + k0, adst1 + bo);
  };

  stage(0, 0);
  __syncthreads();
  int cur = 0;
  for (int kt = 0; kt < NT; ++kt) {
    if (kt + 1 < NT) stage(kt + 1, cur ^ 1);
    const u16* Wb = &Ws[cur][0];
    const u16* Ab = &As[cur][0];
    bf16x8 aa[4], bb[4];
#pragma unroll
    for (int t = 0; t < 4; ++t) {
      aa[t] = *(const bf16x8*)(Ab + (wr * 64 + t * 16 + lr) * 32 + swk);
      bb[t] = *(const bf16x8*)(Wb + (wc * 64 + t * 16 + lr) * 32 + swk);
    }
#pragma unroll
    for (int i = 0; i < 4; ++i)
#pragma unroll
      for (int j = 0; j < 4; ++j)
        acc[i][j] = __builtin_amdgcn_mfma_f32_16x16x32_bf16(aa[i], bb[j], acc[i][j], 0, 0, 0);
    __syncthreads();
    cur ^= 1;
  }

#pragma unroll
  for (int j = 0; j < 4; ++j) {
    const int v = v0 + wc * 64 + j * 16 + lr;
    const float bv = p.bias[v];
#pragma unroll
    for (int i = 0; i < 4; ++i) {
      const int mb = m0 + wr * 64 + i * 16 + (lane >> 4) * 4;
#pragma unroll
      for (int r = 0; r < 4; ++r) {
        const int m = mb + r;
        const float val = acc[i][j][r] + bv;
        if (p.ldc) p.Cf[m * p.ldc + v] = val;
        else p.Cf[(m & (B_ - 1)) * (DEC_T_ * V_) + (m >> 11) * V_ + v] = val;
      }
    }
  }
}

// ---- prep: gate-interleaved bf16 weight + combined bias ---------------------
__global__ void prep_gates_k(const float* Wih, const float* Whh,
                             const float* b1, const float* b2,
                             u16* Wout, float* bsum, int KI, int K) {
  const int j = blockIdx.y;
  const int k = blockIdx.x * 256 + threadIdx.x;
  const int worig = (j & 3) * H_ + (j >> 2);
  const float v = (k < KI) ? Wih[worig * KI + k] : Whh[worig * H_ + (k - KI)];
  Wout[(long)j * K + k] = f2b(v);
  if (k == 0) bsum[j] = b1[worig] + b2[worig];
}

__global__ void cast_k(const float* s, u16* d) {
  const int i = blockIdx.x * 256 + threadIdx.x;
  d[i] = f2b(s[i]);
}

__global__ void init_k(u16* a, u16* b, unsigned* bar) {
  const int i = blockIdx.x * 256 + threadIdx.x;
  a[i] = 0; b[i] = 0;
  if (i < 8) bar[i] = 0u;
}

__global__ void cast_feat_k(const int* f, float* o) {
  const int i = blockIdx.x * 256 + threadIdx.x;
  o[i] = b2f(f2b((float)f[i]));
}

// fused LN stats + apply (both param sets), bf16 in/out
__global__ void ln_k(const u16* hf, const u16* hb,
                     const float* g0, const float* b0,
                     const float* g1, const float* b1,
                     u16* A0, u16* A1) {
  const int b = blockIdx.x, t = threadIdx.x;
  const int k4 = t * 4;
  const u16* src = (k4 < H_) ? (hf + b * H_ + k4) : (hb + b * H_ + (k4 - H_));
  const ushort4 raw = *(const ushort4*)src;
  const float x0 = b2f(raw.x), x1 = b2f(raw.y), x2 = b2f(raw.z), x3 = b2f(raw.w);
  float s = x0 + x1 + x2 + x3;
  float sq = x0 * x0 + x1 * x1 + x2 * x2 + x3 * x3;
#pragma unroll
  for (int off = 32; off; off >>= 1) {
    s += __shfl_down(s, off);
    sq += __shfl_down(sq, off);
  }
  __shared__ float ss[4], ssq[4], smv[2];
  if ((t & 63) == 0) { ss[t >> 6] = s; ssq[t >> 6] = sq; }
  __syncthreads();
  if (t == 0) {
    const float S = ss[0] + ss[1] + ss[2] + ss[3];
    const float SQ = ssq[0] + ssq[1] + ssq[2] + ssq[3];
    const float m = S * (1.f / 1024.f);
    const float var = SQ * (1.f / 1024.f) - m * m;
    smv[0] = m; smv[1] = rsqrtf(var + 1e-5f);
  }
  __syncthreads();
  const float m = smv[0], rs = smv[1];
  const float4 ga = *(const float4*)(g0 + k4), ba = *(const float4*)(b0 + k4);
  const float4 gb = *(const float4*)(g1 + k4), bb = *(const float4*)(b1 + k4);
  ushort4 o0, o1;
  o0.x = f2b((x0 - m) * rs * ga.x + ba.x);
  o0.y = f2b((x1 - m) * rs * ga.y + ba.y);
  o0.z = f2b((x2 - m) * rs * ga.z + ba.z);
  o0.w = f2b((x3 - m) * rs * ga.w + ba.w);
  o1.x = f2b((x0 - m) * rs * gb.x + bb.x);
  o1.y = f2b((x1 - m) * rs * gb.y + bb.y);
  o1.z = f2b((x2 - m) * rs * gb.z + bb.z);
  o1.w = f2b((x3 - m) * rs * gb.w + bb.w);
  *(ushort4*)(A0 + b * 1024 + k4) = o0;
  *(ushort4*)(A1 + b * 1024 + k4) = o1;
}

__global__ void z_k(const float* mu, const float* lv, const float* eps,
                    u16* dz, float* dc) {
  const int i = blockIdx.x * 256 + threadIdx.x;
  const float z = mu[i] + __expf(0.5f * lv[i]) * eps[i];
  dz[i] = f2b(z);
  dc[(i & (H_ - 1)) * B_ + (i >> 9)] = z;   // c transposed [H][B]
}

extern "C" void kernel_launch(void* const* d_in, const int* in_sizes, int n_in,
                              void* d_out, int out_size, void* d_ws, size_t ws_size,
                              hipStream_t stream) {
  const int*   features = (const int*)d_in[0];
  const float* eps      = (const float*)d_in[1];
  const float* emb      = (const float*)d_in[2];
  const float* eWih_f   = (const float*)d_in[3];
  const float* eWhh_f   = (const float*)d_in[4];
  const float* ebih_f   = (const float*)d_in[5];
  const float* ebhh_f   = (const float*)d_in[6];
  const float* eWih_b   = (const float*)d_in[7];
  const float* eWhh_b   = (const float*)d_in[8];
  const float* ebih_b   = (const float*)d_in[9];
  const float* ebhh_b   = (const float*)d_in[10];
  const float* dWhh     = (const float*)d_in[12];
  const float* dbih     = (const float*)d_in[13];
  const float* dbhh     = (const float*)d_in[14];
  const float* mu_ln_g  = (const float*)d_in[15];
  const float* mu_ln_b  = (const float*)d_in[16];
  const float* mu_W     = (const float*)d_in[17];
  const float* mu_b     = (const float*)d_in[18];
  const float* lv_ln_g  = (const float*)d_in[19];
  const float* lv_ln_b  = (const float*)d_in[20];
  const float* lv_W     = (const float*)d_in[21];
  const float* lv_b     = (const float*)d_in[22];
  const float* ff_W     = (const float*)d_in[23];
  const float* ff_b     = (const float*)d_in[24];

  float* of = (float*)d_out;
  float* o_feat = of;
  float* o_fh   = of + (B_ * L_);
  float* o_mu   = o_fh + (long)B_ * DEC_T_ * V_;
  float* o_lv   = o_mu + (long)B_ * H_;

  // ---- ws layout (25.9 MB total) -------------------------------------------
  // hfa hba hfb hbb (8 MB) | Wenc_f Wenc_b (6.29 MB) | Wdec Wff Wmu Wlv embb
  // bsums bar (5.53 MB) | dz (2 MB) | dc (4 MB)
  // Aliases: An0 = hfb..hbb (4 MB, dead post-enc); An1 = Wenc_f.. (4 MB, dead
  // post-enc); dech = ws base, 7*NA*2 B over hfa..Wenc_b (dead during dec/ff).
  u16* hfa = (u16*)d_ws;
  u16* hba = hfa + NA_;
  u16* hfb = hba + NA_;
  u16* hbb = hfb + NA_;
  u16* Wenc_f = hbb + NA_;                  // 2048*768
  u16* Wenc_b = Wenc_f + 2048 * 768;        // 2048*768
  u16* Wdec   = Wenc_b + 2048 * 768;        // 2048*512
  u16* Wff    = Wdec + 2048 * 512;          // 1024*512
  u16* Wmu    = Wff + 1024 * 512;           // 512*1024
  u16* Wlv    = Wmu + 512 * 1024;           // 512*1024
  u16* embb   = Wlv + 512 * 1024;           // 1024*256
  float* bsum_f = (float*)(embb + V_ * E_); // 3 x 2048 fp32
  float* bsum_b = bsum_f + 2048;
  float* bsum_d = bsum_b + 2048;
  unsigned* bar = (unsigned*)(bsum_d + 2048);  // 8 uints: barrier state
  u16* dz     = (u16*)(bar + 8);            // B*H bf16
  float* dc   = (float*)(dz + NA_);         // H x B fp32 (dec c0, transposed)
  u16* An0    = hfb;                        // alias
  u16* An1    = Wenc_f;                     // alias
  u16* dech   = hfa;                        // alias: 7*NA over hfa..Wenc_b

  cast_feat_k<<<dim3(B_ * L_ / 256), dim3(256), 0, stream>>>(features, o_feat);
  init_k<<<dim3(NA_ / 256), dim3(256), 0, stream>>>(hfa, hba, bar);

  prep_gates_k<<<dim3(3, 2048), dim3(256), 0, stream>>>(eWih_f, eWhh_f, ebih_f, ebhh_f, Wenc_f, bsum_f, E_, E_ + H_);
  prep_gates_k<<<dim3(3, 2048), dim3(256), 0, stream>>>(eWih_b, eWhh_b, ebih_b, ebhh_b, Wenc_b, bsum_b, E_, E_ + H_);
  prep_gates_k<<<dim3(2, 2048), dim3(256), 0, stream>>>(nullptr, dWhh, dbih, dbhh, Wdec, bsum_d, 0, H_);
  cast_k<<<dim3(1024 * 512 / 256), dim3(256), 0, stream>>>(ff_W, Wff);
  cast_k<<<dim3(512 * 1024 / 256), dim3(256), 0, stream>>>(mu_W, Wmu);
  cast_k<<<dim3(512 * 1024 / 256), dim3(256), 0, stream>>>(lv_W, Wlv);
  cast_k<<<dim3(V_ * E_ / 256), dim3(256), 0, stream>>>(emb, embb);

  // ---- encoder: ONE persistent launch (32 steps, grid barrier) -------------
  enc_persist_k<<<dim3(512), dim3(256), 0, stream>>>(
      features, embb, Wenc_f, Wenc_b, bsum_f, bsum_b,
      hfa, hfb, hba, hbb, bar);
  // L=32 even -> final fwd h in hfa, bwd h in hba.

  // ---- LN (fused stats+apply) + mu/lv heads --------------------------------
  ln_k<<<dim3(B_), dim3(256), 0, stream>>>(hfa, hba, mu_ln_g, mu_ln_b, lv_ln_g, lv_ln_b, An0, An1);
  {
    OP pm{}, pl{};
    pm.A = An0; pm.W = Wmu; pm.bias = mu_b; pm.Cf = o_mu; pm.ldc = H_; pm.K = 2 * H_;
    pl = pm;
    pl.A = An1; pl.W = Wlv; pl.bias = lv_b; pl.Cf = o_lv;
    out_mfma_k<<<dim3(4, 16, 2), dim3(256), 0, stream>>>(pm, pl);
  }
  z_k<<<dim3(NA_ / 256), dim3(256), 0, stream>>>(o_mu, o_lv, eps, dz, dc);

  // ---- decoder: ONE persistent launch (7 steps, grid barrier) --------------
  dec_persist_k<<<dim3(256), dim3(256), 0, stream>>>(Wdec, bsum_d, dz, dc, dech, bar);

  // ---- ONE batched ff GEMM over all 7 steps --------------------------------
  {
    OP po{};
    po.A = dech; po.W = Wff; po.bias = ff_b;
    po.Cf = o_fh; po.ldc = 0;            // ff (t,b) mode
    po.K = H_;
    out_mfma_k<<<dim3(8, DEC_T_ * 16, 1), dim3(256), 0, stream>>>(po, po);
  }
}

// Round 5
// 1095.411 us; speedup vs baseline: 2.5016x; 2.5016x over previous
//
#include <hip/hip_runtime.h>
#include <hip/hip_bf16.h>
#include <math.h>

#define B_ 2048
#define L_ 32
#define V_ 1024
#define E_ 256
#define H_ 512
#define DEC_T_ 7
#define NA_ (B_ * H_)

typedef unsigned short u16;
typedef unsigned int u32;
using bf16x8 = __attribute__((ext_vector_type(8))) short;
using f32x4  = __attribute__((ext_vector_type(4))) float;

__device__ __forceinline__ u16 f2b(float f) {
  union { float f; u32 i; } x; x.f = f;
  u32 r = x.i + 0x7FFFu + ((x.i >> 16) & 1u);
  return (u16)(r >> 16);
}
__device__ __forceinline__ float b2f(u16 u) {
  union { u32 i; float f; } x; x.i = ((u32)u) << 16; return x.f;
}
__device__ __forceinline__ float sigm(float x) { return 1.f / (1.f + __expf(-x)); }
__device__ __forceinline__ float tanhfast(float x) {
  const float xx = fminf(fmaxf(x, -15.f), 15.f);
  const float e = __expf(2.f * xx);
  return (e - 1.f) / (e + 1.f);
}

// async global->LDS, 16B per lane. dest = wave-uniform base + lane*16.
__device__ __forceinline__ void gl_lds16(const void* g, void* l) {
  __builtin_amdgcn_global_load_lds((const __attribute__((address_space(1))) u32*)g,
                                   (__attribute__((address_space(3))) u32*)l, 16, 0, 0);
}
// coherent variant (SC0): bypass per-CU L1, read XCD-shared L2. Used for h
// tiles written by other blocks on the SAME XCD across the barrier.
__device__ __forceinline__ void gl_lds16c(const void* g, void* l) {
  __builtin_amdgcn_global_load_lds((const __attribute__((address_space(1))) u32*)g,
                                   (__attribute__((address_space(3))) u32*)l, 16, 0, 1);
}

// ---------------------------------------------------------------------------
// Per-XCD monotonic barrier. Group = bid&7 (HW round-robins blocks to XCDs).
// All h producer->consumer pairs are intra-XCD by construction, so NO
// device-scope fence is needed: __syncthreads drains vmcnt (stores land in
// the XCD-shared L2; L1 is write-through), the relaxed agent-scope atomic
// signals arrival at the coherence point WITHOUT any L2 writeback/invalidate
// (R4 post-mortem: __threadfence's per-step L2 invalidate caused 645 MB of W
// refetch = the 2.4 ms). Monotonic counter: no resets, no ABA, replay-safe
// via init_k re-zeroing each call. Bounded spin -> fail visibly, never hang.
// ---------------------------------------------------------------------------
__device__ __forceinline__ void gbar_mono(unsigned* cnt, unsigned target) {
  __syncthreads();
  if (threadIdx.x == 0) {
    __hip_atomic_fetch_add(cnt, 1u, __ATOMIC_RELAXED, __HIP_MEMORY_SCOPE_AGENT);
    for (int it = 0; it < (1 << 22); ++it) {
      if (__hip_atomic_load(cnt, __ATOMIC_RELAXED, __HIP_MEMORY_SCOPE_AGENT) >= target) break;
      __builtin_amdgcn_s_sleep(2);
    }
  }
  asm volatile("" ::: "memory");
  __syncthreads();
}

// ---------------------------------------------------------------------------
// LDS tiles [128 rows][32 bf16] linear, double-buffered; 16B chunks
// XOR-swizzled on the GLOBAL source (linear LDS dest, gl_lds16) and on the
// ds_read address with the same involution -> conflict-free (verified R2).
// Epilogue h-staging uses stride 40 u16 (80B rows): write banks mloc*20%32
// -> 2-way (free); 16B-aligned coalesced reads.
// ---------------------------------------------------------------------------

// Persistent bidirectional encoder: 32 LSTM steps in ONE launch.
// 512 blocks; XCD x (bid&7): dir = x>>2, m-blocks {4(x&3)..+3}, all 16 j.
// h exchange is intra-XCD; c state in registers.
__launch_bounds__(256, 2)
__global__ void enc_persist_k(const int* __restrict__ feat, const u16* __restrict__ emb,
                              const u16* __restrict__ Wf, const u16* __restrict__ Wbk,
                              const float* __restrict__ bsf, const float* __restrict__ bsb,
                              u16* hfa, u16* hfb, u16* hba, u16* hbb,
                              unsigned* bar) {
  __shared__ u16 Wt[2][128 * 32];
  __shared__ u16 At[2][128 * 32];
  const int tid = threadIdx.x;
  const int lane = tid & 63, wave = tid >> 6;
  const int wr = wave & 1, wc = wave >> 1;
  const int bid = blockIdx.x;
  const int xcd = bid & 7;
  const int l = xcd * 64 + (bid >> 3);                // XCD-contiguous logical id
  const int dir = l >> 8;
  const int j0 = (l & 15) * 128;
  const int m0 = (((l >> 6) & 3) * 4 + ((l >> 4) & 3)) * 128;
  const u16* W = dir ? Wbk : Wf;
  const float* bsum = dir ? bsb : bsf;
  u16* hA = dir ? hba : hfa;
  u16* hB = dir ? hbb : hfb;
  unsigned* cnt = bar + xcd * 64;                     // per-XCD counter, 256B apart

  const int lr = lane & 15;
  const int swk = ((lane >> 4) ^ ((lane >> 1) & 3)) * 8;   // swizzled read chunk
  const int srow = wave * 32 + (lane >> 2);
  const int csrc = ((lane & 3) ^ ((lane >> 3) & 3)) * 8;   // swizzled src chunk
  const u16* wsrc0 = W + (j0 + srow) * (E_ + H_) + csrc;
  const u16* wsrc1 = wsrc0 + 16 * (E_ + H_);
  u16* wdst0 = &Wt[0][(wave * 32) * 32];
  u16* wdst1 = wdst0 + 16 * 32;
  u16* adst0 = &At[0][(wave * 32) * 32];
  u16* adst1 = adst0 + 16 * 32;
  u16* hlds = &Wt[0][0];                                   // reused post-K-loop, stride 40
  const int frow0 = (m0 + srow) * L_;
  const int frow1 = (m0 + srow + 16) * L_;
  const int jb_base = j0 + wr * 64 + (lane >> 4) * 4;
  const int n0 = j0 >> 2;                                  // block's 32-wide n range

  float creg[4][4] = {};                                   // cell state, in regs

  for (int s = 0; s < L_; ++s) {
    const int tc = dir ? (L_ - 1 - s) : s;
    const int t0 = feat[frow0 + tc], t1 = feat[frow1 + tc];
    const u16* e0 = emb + t0 * E_ + csrc;
    const u16* e1 = emb + t1 * E_ + csrc;
    const u16* hin = (s & 1) ? hB : hA;
    u16* hout = (s & 1) ? hA : hB;
    const u16* h0 = hin + (m0 + srow) * H_ + csrc - E_;    // h0 + k0 valid for k0 >= E_
    const u16* h1 = h0 + 16 * H_;

    if (s) gbar_mono(cnt, 64u * (unsigned)s);              // h(s-1) visible (intra-XCD)

    // stage kt=0 -> buf0, kt=1 -> buf1 (both k-tiles are in the emb range)
    gl_lds16(wsrc0, wdst0);            gl_lds16(wsrc1, wdst1);
    gl_lds16(e0, adst0);               gl_lds16(e1, adst1);
    gl_lds16(wsrc0 + 32, wdst0 + 4096); gl_lds16(wsrc1 + 32, wdst1 + 4096);
    gl_lds16(e0 + 32, adst0 + 4096);    gl_lds16(e1 + 32, adst1 + 4096);
    __syncthreads();

    f32x4 acc[4][4] = {};
    int cur = 0;
    for (int kt = 0; kt < 24; ++kt) {
      if (kt >= 1 && kt + 1 < 24) {                        // kt=1 pre-staged
        const int k0 = (kt + 1) << 5;
        const int bo = (cur ^ 1) * 4096;
        gl_lds16(wsrc0 + k0, wdst0 + bo);
        gl_lds16(wsrc1 + k0, wdst1 + bo);
        if (k0 < E_) { gl_lds16(e0 + k0, adst0 + bo); gl_lds16(e1 + k0, adst1 + bo); }
        else         { gl_lds16c(h0 + k0, adst0 + bo); gl_lds16c(h1 + k0, adst1 + bo); }
      }
      const u16* Wb2 = &Wt[cur][0];
      const u16* Ab2 = &At[cur][0];
      bf16x8 af[4], bb[4];
#pragma unroll
      for (int t = 0; t < 4; ++t) {
        af[t] = *(const bf16x8*)(Wb2 + (wr * 64 + t * 16 + lr) * 32 + swk);
        bb[t] = *(const bf16x8*)(Ab2 + (wc * 64 + t * 16 + lr) * 32 + swk);
      }
#pragma unroll
      for (int i = 0; i < 4; ++i)
#pragma unroll
        for (int j = 0; j < 4; ++j)
          acc[i][j] = __builtin_amdgcn_mfma_f32_16x16x32_bf16(af[i], bb[j], acc[i][j], 0, 0, 0);
      __syncthreads();                                     // drains staged vmcnt
      cur ^= 1;
    }

    // epilogue: gates -> cell update in regs, h tile via LDS (stride 40)
#pragma unroll
    for (int i = 0; i < 4; ++i) {
      const int jb = jb_base + i * 16;
      const float4 bs = *(const float4*)(bsum + jb);
      const int nloc = (jb - j0) >> 2;                     // 0..31
#pragma unroll
      for (int j = 0; j < 4; ++j) {
        const int mloc = wc * 64 + j * 16 + lr;
        const float gi = acc[i][j][0] + bs.x;
        const float gf = acc[i][j][1] + bs.y;
        const float gg = acc[i][j][2] + bs.z;
        const float go = acc[i][j][3] + bs.w;
        const float cn = sigm(gf) * creg[i][j] + sigm(gi) * tanhfast(gg);
        creg[i][j] = cn;
        hlds[mloc * 40 + nloc] = f2b(sigm(go) * tanhfast(cn));
      }
    }
    __syncthreads();
    // coalesced h write: 512 16B chunks, 2 per thread
#pragma unroll
    for (int cc = 0; cc < 2; ++cc) {
      const int ch = tid + cc * 256;
      const int row = ch >> 2, cpos = (ch & 3) * 8;
      *(uint4*)(hout + (m0 + row) * H_ + n0 + cpos) = *(const uint4*)(hlds + row * 40 + cpos);
    }
  }
}

// Persistent decoder: 7 LSTM steps in ONE launch. 256 blocks; XCD x: m-blocks
// {2x,2x+1}, all 16 j -> intra-XCD h exchange. c0 = z from dc (fp32 [n][m]).
__launch_bounds__(256, 2)
__global__ void dec_persist_k(const u16* __restrict__ Wd, const float* __restrict__ bsd,
                              const u16* __restrict__ dz, const float* __restrict__ dcc,
                              u16* dech, unsigned* bar) {
  __shared__ u16 Wt[2][128 * 32];
  __shared__ u16 At[2][128 * 32];
  const int tid = threadIdx.x;
  const int lane = tid & 63, wave = tid >> 6;
  const int wr = wave & 1, wc = wave >> 1;
  const int bid = blockIdx.x;
  const int xcd = bid & 7;
  const int l = xcd * 32 + (bid >> 3);
  const int j0 = (l & 15) * 128;
  const int m0 = ((l >> 5) * 2 + ((l >> 4) & 1)) * 128;
  unsigned* cnt = bar + (8 + xcd) * 64;

  const int lr = lane & 15;
  const int swk = ((lane >> 4) ^ ((lane >> 1) & 3)) * 8;
  const int srow = wave * 32 + (lane >> 2);
  const int csrc = ((lane & 3) ^ ((lane >> 3) & 3)) * 8;
  const u16* wsrc0 = Wd + (j0 + srow) * H_ + csrc;
  const u16* wsrc1 = wsrc0 + 16 * H_;
  u16* wdst0 = &Wt[0][(wave * 32) * 32];
  u16* wdst1 = wdst0 + 16 * 32;
  u16* adst0 = &At[0][(wave * 32) * 32];
  u16* adst1 = adst0 + 16 * 32;
  u16* hlds = &Wt[0][0];
  const int jb_base = j0 + wr * 64 + (lane >> 4) * 4;
  const int n0 = j0 >> 2;

  float creg[4][4];
#pragma unroll
  for (int i = 0; i < 4; ++i) {
    const int n = (jb_base + i * 16) >> 2;
#pragma unroll
    for (int j = 0; j < 4; ++j)
      creg[i][j] = dcc[n * B_ + (m0 + wc * 64 + j * 16 + lr)];
  }

  for (int t = 0; t < DEC_T_; ++t) {
    const u16* hin = t ? (dech + (long)(t - 1) * NA_) : dz;
    u16* hout = dech + (long)t * NA_;
    const u16* h0 = hin + (m0 + srow) * H_ + csrc;
    const u16* h1 = h0 + 16 * H_;

    if (t) gbar_mono(cnt, 32u * (unsigned)t);

    gl_lds16(wsrc0, wdst0);            gl_lds16(wsrc1, wdst1);
    gl_lds16c(h0, adst0);              gl_lds16c(h1, adst1);
    gl_lds16(wsrc0 + 32, wdst0 + 4096); gl_lds16(wsrc1 + 32, wdst1 + 4096);
    gl_lds16c(h0 + 32, adst0 + 4096);   gl_lds16c(h1 + 32, adst1 + 4096);
    __syncthreads();

    f32x4 acc[4][4] = {};
    int cur = 0;
    for (int kt = 0; kt < 16; ++kt) {
      if (kt >= 1 && kt + 1 < 16) {
        const int k0 = (kt + 1) << 5;
        const int bo = (cur ^ 1) * 4096;
        gl_lds16(wsrc0 + k0, wdst0 + bo);
        gl_lds16(wsrc1 + k0, wdst1 + bo);
        gl_lds16c(h0 + k0, adst0 + bo);
        gl_lds16c(h1 + k0, adst1 + bo);
      }
      const u16* Wb2 = &Wt[cur][0];
      const u16* Ab2 = &At[cur][0];
      bf16x8 af[4], bb[4];
#pragma unroll
      for (int tt = 0; tt < 4; ++tt) {
        af[tt] = *(const bf16x8*)(Wb2 + (wr * 64 + tt * 16 + lr) * 32 + swk);
        bb[tt] = *(const bf16x8*)(Ab2 + (wc * 64 + tt * 16 + lr) * 32 + swk);
      }
#pragma unroll
      for (int i = 0; i < 4; ++i)
#pragma unroll
        for (int j = 0; j < 4; ++j)
          acc[i][j] = __builtin_amdgcn_mfma_f32_16x16x32_bf16(af[i], bb[j], acc[i][j], 0, 0, 0);
      __syncthreads();
      cur ^= 1;
    }

#pragma unroll
    for (int i = 0; i < 4; ++i) {
      const int jb = jb_base + i * 16;
      const float4 bs = *(const float4*)(bsd + jb);
      const int nloc = (jb - j0) >> 2;
#pragma unroll
      for (int j = 0; j < 4; ++j) {
        const int mloc = wc * 64 + j * 16 + lr;
        const float gi = acc[i][j][0] + bs.x;
        const float gf = acc[i][j][1] + bs.y;
        const float gg = acc[i][j][2] + bs.z;
        const float go = acc[i][j][3] + bs.w;
        const float cn = sigm(gf) * creg[i][j] + sigm(gi) * tanhfast(gg);
        creg[i][j] = cn;
        hlds[mloc * 40 + nloc] = f2b(sigm(go) * tanhfast(cn));
      }
    }
    __syncthreads();
#pragma unroll
    for (int cc = 0; cc < 2; ++cc) {
      const int ch = tid + cc * 256;
      const int row = ch >> 2, cpos = (ch & 3) * 8;
      *(uint4*)(hout + (m0 + row) * H_ + n0 + cpos) = *(const uint4*)(hlds + row * 40 + cpos);
    }
  }
}

// ---------------------------------------------------------------------------
// Plain bf16 GEMM + bias: C[m][v] = A[m]*W[v] + bias[v], fp32 out.
// ldc==0 => ff mode: row m encodes (t=m>>11, b=m&2047), C index b*7V+t*V+v.
// ---------------------------------------------------------------------------
struct OP {
  const u16* A;       // M x K bf16
  const u16* W;       // N x K bf16
  const float* bias;  // N fp32
  float* Cf;
  int ldc;            // 0 => ff (t,b) mode
  int K;
};

__launch_bounds__(256)
__global__ void out_mfma_k(OP p0, OP p1) {
  OP p = blockIdx.z ? p1 : p0;
  __shared__ u16 Ws[2][128 * 32];
  __shared__ u16 As[2][128 * 32];
  const int tid = threadIdx.x;
  const int lane = tid & 63, wave = tid >> 6;
  const int wr = wave & 1, wc = wave >> 1;
  const int v0 = blockIdx.x * 128, m0 = blockIdx.y * 128;
  const int lr = lane & 15;
  const int swk = ((lane >> 4) ^ ((lane >> 1) & 3)) * 8;

  const int srow = wave * 32 + (lane >> 2);
  const int csrc = ((lane & 3) ^ ((lane >> 3) & 3)) * 8;
  const u16* wsrc0 = p.W + (v0 + srow) * p.K + csrc;
  const u16* wsrc1 = wsrc0 + 16 * p.K;
  const u16* asrc0 = p.A + (m0 + srow) * p.K + csrc;
  const u16* asrc1 = asrc0 + 16 * p.K;
  u16* wdst0 = &Ws[0][(wave * 32) * 32];
  u16* wdst1 = wdst0 + 16 * 32;
  u16* adst0 = &As[0][(wave * 32) * 32];
  u16* adst1 = adst0 + 16 * 32;

  f32x4 acc[4][4] = {};
  const int NT = p.K >> 5;

  auto stage = [&](int kt, int buf) {
    const int k0 = kt << 5;
    const int bo = buf * 4096;
    gl_lds16(wsrc0 + k0, wdst0 + bo);
    gl_lds16(wsrc1 + k0, wdst1 + bo);
    gl_lds16(asrc0 + k0, adst0 + bo);
    gl_lds16(asrc1 + k0, adst1 + bo);
  };

  stage(0, 0);
  __syncthreads();
  int cur = 0;
  for (int kt = 0; kt < NT; ++kt) {
    if (kt + 1 < NT) stage(kt + 1, cur ^ 1);
    const u16* Wb = &Ws[cur][0];
    const u16* Ab = &As[cur][0];
    bf16x8 aa[4], bb[4];
#pragma unroll
    for (int t = 0; t < 4; ++t) {
      aa[t] = *(const bf16x8*)(Ab + (wr * 64 + t * 16 + lr) * 32 + swk);
      bb[t] = *(const bf16x8*)(Wb + (wc * 64 + t * 16 + lr) * 32 + swk);
    }
#pragma unroll
    for (int i = 0; i < 4; ++i)
#pragma unroll
      for (int j = 0; j < 4; ++j)
        acc[i][j] = __builtin_amdgcn_mfma_f32_16x16x32_bf16(aa[i], bb[j], acc[i][j], 0, 0, 0);
    __syncthreads();
    cur ^= 1;
  }

#pragma unroll
  for (int j = 0; j < 4; ++j) {
    const int v = v0 + wc * 64 + j * 16 + lr;
    const float bv = p.bias[v];
#pragma unroll
    for (int i = 0; i < 4; ++i) {
      const int mb = m0 + wr * 64 + i * 16 + (lane >> 4) * 4;
#pragma unroll
      for (int r = 0; r < 4; ++r) {
        const int m = mb + r;
        const float val = acc[i][j][r] + bv;
        if (p.ldc) p.Cf[m * p.ldc + v] = val;
        else p.Cf[(m & (B_ - 1)) * (DEC_T_ * V_) + (m >> 11) * V_ + v] = val;
      }
    }
  }
}

// ---- prep: gate-interleaved bf16 weight + combined bias ---------------------
__global__ void prep_gates_k(const float* Wih, const float* Whh,
                             const float* b1, const float* b2,
                             u16* Wout, float* bsum, int KI, int K) {
  const int j = blockIdx.y;
  const int k = blockIdx.x * 256 + threadIdx.x;
  const int worig = (j & 3) * H_ + (j >> 2);
  const float v = (k < KI) ? Wih[worig * KI + k] : Whh[worig * H_ + (k - KI)];
  Wout[(long)j * K + k] = f2b(v);
  if (k == 0) bsum[j] = b1[worig] + b2[worig];
}

__global__ void cast_k(const float* s, u16* d) {
  const int i = blockIdx.x * 256 + threadIdx.x;
  d[i] = f2b(s[i]);
}

__global__ void init_k(u16* a, u16* b, unsigned* bar) {
  const int i = blockIdx.x * 256 + threadIdx.x;
  a[i] = 0; b[i] = 0;
  if (i < 1024) bar[i] = 0u;
}

__global__ void cast_feat_k(const int* f, float* o) {
  const int i = blockIdx.x * 256 + threadIdx.x;
  o[i] = b2f(f2b((float)f[i]));
}

// fused LN stats + apply (both param sets), bf16 in/out
__global__ void ln_k(const u16* hf, const u16* hb,
                     const float* g0, const float* b0,
                     const float* g1, const float* b1,
                     u16* A0, u16* A1) {
  const int b = blockIdx.x, t = threadIdx.x;
  const int k4 = t * 4;
  const u16* src = (k4 < H_) ? (hf + b * H_ + k4) : (hb + b * H_ + (k4 - H_));
  const ushort4 raw = *(const ushort4*)src;
  const float x0 = b2f(raw.x), x1 = b2f(raw.y), x2 = b2f(raw.z), x3 = b2f(raw.w);
  float s = x0 + x1 + x2 + x3;
  float sq = x0 * x0 + x1 * x1 + x2 * x2 + x3 * x3;
#pragma unroll
  for (int off = 32; off; off >>= 1) {
    s += __shfl_down(s, off);
    sq += __shfl_down(sq, off);
  }
  __shared__ float ss[4], ssq[4], smv[2];
  if ((t & 63) == 0) { ss[t >> 6] = s; ssq[t >> 6] = sq; }
  __syncthreads();
  if (t == 0) {
    const float S = ss[0] + ss[1] + ss[2] + ss[3];
    const float SQ = ssq[0] + ssq[1] + ssq[2] + ssq[3];
    const float m = S * (1.f / 1024.f);
    const float var = SQ * (1.f / 1024.f) - m * m;
    smv[0] = m; smv[1] = rsqrtf(var + 1e-5f);
  }
  __syncthreads();
  const float m = smv[0], rs = smv[1];
  const float4 ga = *(const float4*)(g0 + k4), ba = *(const float4*)(b0 + k4);
  const float4 gb = *(const float4*)(g1 + k4), bb = *(const float4*)(b1 + k4);
  ushort4 o0, o1;
  o0.x = f2b((x0 - m) * rs * ga.x + ba.x);
  o0.y = f2b((x1 - m) * rs * ga.y + ba.y);
  o0.z = f2b((x2 - m) * rs * ga.z + ba.z);
  o0.w = f2b((x3 - m) * rs * ga.w + ba.w);
  o1.x = f2b((x0 - m) * rs * gb.x + bb.x);
  o1.y = f2b((x1 - m) * rs * gb.y + bb.y);
  o1.z = f2b((x2 - m) * rs * gb.z + bb.z);
  o1.w = f2b((x3 - m) * rs * gb.w + bb.w);
  *(ushort4*)(A0 + b * 1024 + k4) = o0;
  *(ushort4*)(A1 + b * 1024 + k4) = o1;
}

__global__ void z_k(const float* mu, const float* lv, const float* eps,
                    u16* dz, float* dc) {
  const int i = blockIdx.x * 256 + threadIdx.x;
  const float z = mu[i] + __expf(0.5f * lv[i]) * eps[i];
  dz[i] = f2b(z);
  dc[(i & (H_ - 1)) * B_ + (i >> 9)] = z;   // c transposed [H][B]
}

extern "C" void kernel_launch(void* const* d_in, const int* in_sizes, int n_in,
                              void* d_out, int out_size, void* d_ws, size_t ws_size,
                              hipStream_t stream) {
  const int*   features = (const int*)d_in[0];
  const float* eps      = (const float*)d_in[1];
  const float* emb      = (const float*)d_in[2];
  const float* eWih_f   = (const float*)d_in[3];
  const float* eWhh_f   = (const float*)d_in[4];
  const float* ebih_f   = (const float*)d_in[5];
  const float* ebhh_f   = (const float*)d_in[6];
  const float* eWih_b   = (const float*)d_in[7];
  const float* eWhh_b   = (const float*)d_in[8];
  const float* ebih_b   = (const float*)d_in[9];
  const float* ebhh_b   = (const float*)d_in[10];
  const float* dWhh     = (const float*)d_in[12];
  const float* dbih     = (const float*)d_in[13];
  const float* dbhh     = (const float*)d_in[14];
  const float* mu_ln_g  = (const float*)d_in[15];
  const float* mu_ln_b  = (const float*)d_in[16];
  const float* mu_W     = (const float*)d_in[17];
  const float* mu_b     = (const float*)d_in[18];
  const float* lv_ln_g  = (const float*)d_in[19];
  const float* lv_ln_b  = (const float*)d_in[20];
  const float* lv_W     = (const float*)d_in[21];
  const float* lv_b     = (const float*)d_in[22];
  const float* ff_W     = (const float*)d_in[23];
  const float* ff_b     = (const float*)d_in[24];

  float* of = (float*)d_out;
  float* o_feat = of;
  float* o_fh   = of + (B_ * L_);
  float* o_mu   = o_fh + (long)B_ * DEC_T_ * V_;
  float* o_lv   = o_mu + (long)B_ * H_;

  // ---- ws layout (~25.9 MB) ------------------------------------------------
  // hfa hba hfb hbb (8 MB) | Wenc_f Wenc_b (6.29 MB) | Wdec Wff Wmu Wlv embb
  // bsums bar(4KB) | dz (2 MB) | dc (4 MB)
  // Aliases: An0 = hfb..hbb; An1 = Wenc_f..; dech = hfa.. (all dead by use).
  u16* hfa = (u16*)d_ws;
  u16* hba = hfa + NA_;
  u16* hfb = hba + NA_;
  u16* hbb = hfb + NA_;
  u16* Wenc_f = hbb + NA_;                  // 2048*768
  u16* Wenc_b = Wenc_f + 2048 * 768;        // 2048*768
  u16* Wdec   = Wenc_b + 2048 * 768;        // 2048*512
  u16* Wff    = Wdec + 2048 * 512;          // 1024*512
  u16* Wmu    = Wff + 1024 * 512;           // 512*1024
  u16* Wlv    = Wmu + 512 * 1024;           // 512*1024
  u16* embb   = Wlv + 512 * 1024;           // 1024*256
  float* bsum_f = (float*)(embb + V_ * E_); // 3 x 2048 fp32
  float* bsum_b = bsum_f + 2048;
  float* bsum_d = bsum_b + 2048;
  unsigned* bar = (unsigned*)(bsum_d + 2048);  // 1024 uints: 16 groups x 64
  u16* dz     = (u16*)(bar + 1024);         // B*H bf16
  float* dc   = (float*)(dz + NA_);         // H x B fp32 (dec c0, transposed)
  u16* An0    = hfb;                        // alias
  u16* An1    = Wenc_f;                     // alias
  u16* dech   = hfa;                        // alias: 7*NA over hfa..Wenc_b

  cast_feat_k<<<dim3(B_ * L_ / 256), dim3(256), 0, stream>>>(features, o_feat);
  init_k<<<dim3(NA_ / 256), dim3(256), 0, stream>>>(hfa, hba, bar);

  prep_gates_k<<<dim3(3, 2048), dim3(256), 0, stream>>>(eWih_f, eWhh_f, ebih_f, ebhh_f, Wenc_f, bsum_f, E_, E_ + H_);
  prep_gates_k<<<dim3(3, 2048), dim3(256), 0, stream>>>(eWih_b, eWhh_b, ebih_b, ebhh_b, Wenc_b, bsum_b, E_, E_ + H_);
  prep_gates_k<<<dim3(2, 2048), dim3(256), 0, stream>>>(nullptr, dWhh, dbih, dbhh, Wdec, bsum_d, 0, H_);
  cast_k<<<dim3(1024 * 512 / 256), dim3(256), 0, stream>>>(ff_W, Wff);
  cast_k<<<dim3(512 * 1024 / 256), dim3(256), 0, stream>>>(mu_W, Wmu);
  cast_k<<<dim3(512 * 1024 / 256), dim3(256), 0, stream>>>(lv_W, Wlv);
  cast_k<<<dim3(V_ * E_ / 256), dim3(256), 0, stream>>>(emb, embb);

  // ---- encoder: ONE persistent launch (32 steps, per-XCD barriers) ---------
  enc_persist_k<<<dim3(512), dim3(256), 0, stream>>>(
      features, embb, Wenc_f, Wenc_b, bsum_f, bsum_b,
      hfa, hfb, hba, hbb, bar);
  // L=32 even -> final fwd h in hfa, bwd h in hba.

  // ---- LN (fused stats+apply) + mu/lv heads --------------------------------
  ln_k<<<dim3(B_), dim3(256), 0, stream>>>(hfa, hba, mu_ln_g, mu_ln_b, lv_ln_g, lv_ln_b, An0, An1);
  {
    OP pm{}, pl{};
    pm.A = An0; pm.W = Wmu; pm.bias = mu_b; pm.Cf = o_mu; pm.ldc = H_; pm.K = 2 * H_;
    pl = pm;
    pl.A = An1; pl.W = Wlv; pl.bias = lv_b; pl.Cf = o_lv;
    out_mfma_k<<<dim3(4, 16, 2), dim3(256), 0, stream>>>(pm, pl);
  }
  z_k<<<dim3(NA_ / 256), dim3(256), 0, stream>>>(o_mu, o_lv, eps, dz, dc);

  // ---- decoder: ONE persistent launch (7 steps, per-XCD barriers) ----------
  dec_persist_k<<<dim3(256), dim3(256), 0, stream>>>(Wdec, bsum_d, dz, dc, dech, bar);

  // ---- ONE batched ff GEMM over all 7 steps --------------------------------
  {
    OP po{};
    po.A = dech; po.W = Wff; po.bias = ff_b;
    po.Cf = o_fh; po.ldc = 0;            // ff (t,b) mode
    po.K = H_;
    out_mfma_k<<<dim3(8, DEC_T_ * 16, 1), dim3(256), 0, stream>>>(po, po);
  }
}